// Round 1
// baseline (199.808 us; speedup 1.0000x reference)
//
#include <hip/hip_runtime.h>
#include <hip/hip_bf16.h>

typedef float  f32x4  __attribute__((ext_vector_type(4)));
typedef __bf16 bf16x8 __attribute__((ext_vector_type(8)));

#define AS1 __attribute__((address_space(1)))
#define AS3 __attribute__((address_space(3)))

__device__ __forceinline__ void async_load16(const void* g, void* lds) {
    __builtin_amdgcn_global_load_lds((const AS1 unsigned int*)g,
                                     (AS3 unsigned int*)lds, 16, 0, 0);
}

// ---------------------------------------------------------------------------
// Kernel 0: WkT[c][k] = bf16(Wk[k][c]).  Wk: [768][1024] f32 -> WkT: [1024][768] bf16
// ---------------------------------------------------------------------------
__global__ void transpose_wk(const float* __restrict__ wk, __bf16* __restrict__ wkt) {
    __shared__ __bf16 tile[32][33];
    const int k0 = blockIdx.x * 32;   // 24 blocks
    const int c0 = blockIdx.y * 32;   // 32 blocks
    const int tx = threadIdx.x & 31;
    const int ty = threadIdx.x >> 5;  // 0..7
#pragma unroll
    for (int i = 0; i < 32; i += 8)
        tile[ty + i][tx] = (__bf16)wk[(size_t)(k0 + ty + i) * 1024 + c0 + tx];
    __syncthreads();
#pragma unroll
    for (int i = 0; i < 32; i += 8)
        wkt[(size_t)(c0 + ty + i) * 768 + k0 + tx] = tile[tx][ty + i];
}

// ---------------------------------------------------------------------------
// Kernel 1: kv[m][c] = bf16( sum_k x[m][k]*Wk[k][c] + bk[c] )
// M=32768, K=768, N=1024.  BM=BN=128, BK=64, 256 threads (4 waves, 2x2 of 64x64)
// ---------------------------------------------------------------------------
__global__ __launch_bounds__(256) void gemm_kv(const float* __restrict__ x,
                                               const __bf16* __restrict__ wkt,
                                               const float* __restrict__ bk,
                                               __bf16* __restrict__ kv) {
    constexpr int K = 768, NN = 1024;
    __shared__ __bf16 Alds[128 * 64];  // [row][k] 16KB
    __shared__ __bf16 Blds[128 * 64];  // [col][k] 16KB

    const int t  = threadIdx.x;
    const int l  = t & 63;
    const int w  = t >> 6;
    const int tm = blockIdx.x >> 3;   // 0..255
    const int tn = blockIdx.x & 7;    // 0..7
    const int m0 = tm * 128, n0 = tn * 128;
    const int wr = (w >> 1) * 64, wc = (w & 1) * 64;

    const int srow = t >> 3;        // 0..31
    const int scol = (t & 7) * 8;   // 0..56 step 8

    f32x4 acc[4][4];
#pragma unroll
    for (int i = 0; i < 4; ++i)
#pragma unroll
        for (int j = 0; j < 4; ++j) acc[i][j] = (f32x4)0.0f;

    for (int kt = 0; kt < K; kt += 64) {
        // ---- stage B via async global->LDS (bf16 source)
#pragma unroll
        for (int i = 0; i < 4; ++i) {
            const int col = i * 32 + srow;
            async_load16(&wkt[(size_t)(n0 + col) * K + kt + scol],
                         &Blds[col * 64 + scol]);
        }
        // ---- stage A: f32 load -> bf16 convert -> ds_write
        float4 a0[4], a1[4];
#pragma unroll
        for (int i = 0; i < 4; ++i) {
            const int row = i * 32 + srow;
            const float* src = &x[(size_t)(m0 + row) * K + kt + scol];
            a0[i] = *(const float4*)(src);
            a1[i] = *(const float4*)(src + 4);
        }
#pragma unroll
        for (int i = 0; i < 4; ++i) {
            const int row = i * 32 + srow;
            bf16x8 v;
            v[0] = (__bf16)a0[i].x; v[1] = (__bf16)a0[i].y;
            v[2] = (__bf16)a0[i].z; v[3] = (__bf16)a0[i].w;
            v[4] = (__bf16)a1[i].x; v[5] = (__bf16)a1[i].y;
            v[6] = (__bf16)a1[i].z; v[7] = (__bf16)a1[i].w;
            *(bf16x8*)&Alds[row * 64 + scol] = v;
        }
        asm volatile("s_waitcnt vmcnt(0)" ::: "memory");
        __syncthreads();

        // ---- compute: 2 k-halves x 4x4 MFMA
#pragma unroll
        for (int ko = 0; ko < 64; ko += 32) {
            const int rbase = l & 15;
            const int kk = ko + (l >> 4) * 8;
            bf16x8 af[4], bfr[4];
#pragma unroll
            for (int i = 0; i < 4; ++i)
                af[i] = *(const bf16x8*)&Alds[(wr + i * 16 + rbase) * 64 + kk];
#pragma unroll
            for (int j = 0; j < 4; ++j)
                bfr[j] = *(const bf16x8*)&Blds[(wc + j * 16 + rbase) * 64 + kk];
#pragma unroll
            for (int i = 0; i < 4; ++i)
#pragma unroll
                for (int j = 0; j < 4; ++j)
                    acc[i][j] = __builtin_amdgcn_mfma_f32_16x16x32_bf16(
                        af[i], bfr[j], acc[i][j], 0, 0, 0);
        }
        __syncthreads();
    }

    // ---- epilogue: C/D layout col=lane&15, row=(lane>>4)*4+reg
#pragma unroll
    for (int j = 0; j < 4; ++j) {
        const int col = n0 + wc + j * 16 + (l & 15);
        const float bkv = bk[col];
#pragma unroll
        for (int i = 0; i < 4; ++i) {
            const int row0 = m0 + wr + i * 16 + (l >> 4) * 4;
#pragma unroll
            for (int r = 0; r < 4; ++r)
                kv[(size_t)(row0 + r) * NN + col] = (__bf16)(acc[i][j][r] + bkv);
        }
    }
}

// ---------------------------------------------------------------------------
// Kernel 2: per (b,h): logits -> masked softmax -> weighted sum.
// 512 blocks of 256 threads.
// ---------------------------------------------------------------------------
__global__ __launch_bounds__(256) void attn_kernel(const __bf16* __restrict__ kv,
                                                   const float* __restrict__ q_emb,
                                                   const int* __restrict__ eos_idx,
                                                   float* __restrict__ out) {
    __shared__ float qlds[4 * 64];
    __shared__ float plds[4 * 1024];
    __shared__ float ssum[4];

    const int t = threadIdx.x;
    const int b = blockIdx.x >> 4;
    const int h = blockIdx.x & 15;
    const int eos = eos_idx[b];

    // q scaled by D^-0.5 = 1/8
    qlds[t] = q_emb[(size_t)h * 256 + t] * 0.125f;
    __syncthreads();

    const __bf16* kvb = kv + (size_t)b * 1024 * 1024 + h * 64;

    // ---- pass 1: logits[s][n]
#pragma unroll
    for (int i = 0; i < 4; ++i) {
        const int n = t + i * 256;
        float d0 = 0.f, d1 = 0.f, d2 = 0.f, d3 = 0.f;
        if (n <= eos) {
            const bf16x8* row = (const bf16x8*)(kvb + (size_t)n * 1024);
#pragma unroll
            for (int c = 0; c < 8; ++c) {
                bf16x8 v = row[c];
#pragma unroll
                for (int j = 0; j < 8; ++j) {
                    const float f = (float)v[j];
                    d0 += qlds[0 * 64 + c * 8 + j] * f;
                    d1 += qlds[1 * 64 + c * 8 + j] * f;
                    d2 += qlds[2 * 64 + c * 8 + j] * f;
                    d3 += qlds[3 * 64 + c * 8 + j] * f;
                }
            }
        } else {
            d0 = d1 = d2 = d3 = -INFINITY;
        }
        plds[0 * 1024 + n] = d0;
        plds[1 * 1024 + n] = d1;
        plds[2 * 1024 + n] = d2;
        plds[3 * 1024 + n] = d3;
    }
    __syncthreads();

    // ---- softmax: wave w handles subhead s=w
    const int w = t >> 6, l = t & 63;
    {
        float m = -INFINITY;
#pragma unroll
        for (int i = 0; i < 16; ++i) m = fmaxf(m, plds[w * 1024 + l + i * 64]);
#pragma unroll
        for (int off = 32; off; off >>= 1) m = fmaxf(m, __shfl_xor(m, off));
        float sum = 0.f;
#pragma unroll
        for (int i = 0; i < 16; ++i) {
            const int n = l + i * 64;
            const float p = __expf(plds[w * 1024 + n] - m);  // exp(-inf)=0
            plds[w * 1024 + n] = p;
            sum += p;
        }
#pragma unroll
        for (int off = 32; off; off >>= 1) sum += __shfl_xor(sum, off);
        if (l == 0) ssum[w] = sum;
    }
    __syncthreads();

    // ---- pass 2: out[s][d] = sum_n p[s][n]*kv[n][d] / ssum[s]
    const int s = t >> 6, d = t & 63;
    const __bf16* col = kvb + d;
    float acc = 0.f;
    int n = 0;
    for (; n + 4 <= eos + 1; n += 4) {
        const float f0 = (float)col[(size_t)(n + 0) * 1024];
        const float f1 = (float)col[(size_t)(n + 1) * 1024];
        const float f2 = (float)col[(size_t)(n + 2) * 1024];
        const float f3 = (float)col[(size_t)(n + 3) * 1024];
        acc += plds[s * 1024 + n + 0] * f0 + plds[s * 1024 + n + 1] * f1 +
               plds[s * 1024 + n + 2] * f2 + plds[s * 1024 + n + 3] * f3;
    }
    for (; n <= eos; ++n) acc += plds[s * 1024 + n] * (float)col[(size_t)n * 1024];

    out[((size_t)b * 64 + h * 4 + s) * 64 + d] = acc / ssum[s];
}

// ---------------------------------------------------------------------------
extern "C" void kernel_launch(void* const* d_in, const int* in_sizes, int n_in,
                              void* d_out, int out_size, void* d_ws, size_t ws_size,
                              hipStream_t stream) {
    const float* x     = (const float*)d_in[0];   // (32,1024,768)
    const int*   eos   = (const int*)d_in[1];     // (32,)
    const float* q_emb = (const float*)d_in[2];   // (16,4,64)
    const float* Wk    = (const float*)d_in[3];   // (768,1024)
    const float* bk    = (const float*)d_in[4];   // (1024,)
    float* out = (float*)d_out;

    __bf16* kv  = (__bf16*)d_ws;                              // 67,108,864 B
    __bf16* wkt = (__bf16*)((char*)d_ws + (size_t)67108864);  // 1,572,864 B

    transpose_wk<<<dim3(24, 32), 256, 0, stream>>>(Wk, wkt);
    gemm_kv<<<dim3(2048), 256, 0, stream>>>(x, wkt, bk, kv);
    attn_kernel<<<dim3(512), 256, 0, stream>>>(kv, q_emb, eos, out);
}

// Round 2
// 155.762 us; speedup vs baseline: 1.2828x; 1.2828x over previous
//
#include <hip/hip_runtime.h>
#include <hip/hip_bf16.h>

typedef float  f32x4  __attribute__((ext_vector_type(4)));
typedef __bf16 bf16x8 __attribute__((ext_vector_type(8)));

#define AS1 __attribute__((address_space(1)))
#define AS3 __attribute__((address_space(3)))

__device__ __forceinline__ void async_load16(const void* g, void* lds) {
    __builtin_amdgcn_global_load_lds((const AS1 unsigned int*)g,
                                     (AS3 unsigned int*)lds, 16, 0, 0);
}

// ---------------------------------------------------------------------------
// Kernel 0: WkT[c][k] = bf16(Wk[k][c]).  Wk: [768][1024] f32 -> WkT: [1024][768] bf16
// ---------------------------------------------------------------------------
__global__ void transpose_wk(const float* __restrict__ wk, __bf16* __restrict__ wkt) {
    __shared__ __bf16 tile[32][33];
    const int k0 = blockIdx.x * 32;   // 24 blocks
    const int c0 = blockIdx.y * 32;   // 32 blocks
    const int tx = threadIdx.x & 31;
    const int ty = threadIdx.x >> 5;  // 0..7
#pragma unroll
    for (int i = 0; i < 32; i += 8)
        tile[ty + i][tx] = (__bf16)wk[(size_t)(k0 + ty + i) * 1024 + c0 + tx];
    __syncthreads();
#pragma unroll
    for (int i = 0; i < 32; i += 8)
        wkt[(size_t)(c0 + ty + i) * 768 + k0 + tx] = tile[tx][ty + i];
}

// ---------------------------------------------------------------------------
// Kernel 1: kv[m][c] = bf16( sum_k x[m][k]*Wk[k][c] + bk[c] )
// M=32768, K=768, N=1024.  BM=128, BN=256, BK=64, 512 threads (8 waves, 2x4)
// XCD-swizzled so the 4 n-blocks of one m-tile run consecutively on one XCD.
// ---------------------------------------------------------------------------
__global__ __launch_bounds__(512) void gemm_kv(const float* __restrict__ x,
                                               const __bf16* __restrict__ wkt,
                                               const float* __restrict__ bk,
                                               __bf16* __restrict__ kv) {
    constexpr int K = 768, NN = 1024;
    __shared__ __bf16 Alds[128 * 64];  // [row][k] 16KB
    __shared__ __bf16 Blds[256 * 64];  // [col][k] 32KB

    const int t = threadIdx.x;
    const int l = t & 63;
    const int w = t >> 6;                               // 0..7
    // bijective XCD swizzle: 1024 blocks, 8 XCDs, 128 vids per XCD
    const int vid = ((blockIdx.x & 7) << 7) + (blockIdx.x >> 3);
    const int tm = vid >> 2;                            // 0..255
    const int tn = vid & 3;                             // 0..3
    const int m0 = tm * 128, n0 = tn * 256;
    const int wr = (w >> 2) * 64;                       // {0,64}
    const int wc = (w & 3) * 64;                        // {0,64,128,192}

    const int srow = t >> 3;        // 0..63
    const int scol = (t & 7) * 8;   // 0..56 step 8

    f32x4 acc[4][4];
#pragma unroll
    for (int i = 0; i < 4; ++i)
#pragma unroll
        for (int j = 0; j < 4; ++j) acc[i][j] = (f32x4)0.0f;

    for (int kt = 0; kt < K; kt += 64) {
        // ---- stage B (256x64 bf16) via async global->LDS
#pragma unroll
        for (int i = 0; i < 4; ++i) {
            const int col = i * 64 + srow;
            async_load16(&wkt[(size_t)(n0 + col) * K + kt + scol],
                         &Blds[col * 64 + scol]);
        }
        // ---- stage A (128x64): f32 load -> bf16 convert -> ds_write
        const float* s0 = &x[(size_t)(m0 + srow) * K + kt + scol];
        const float* s1 = &x[(size_t)(m0 + srow + 64) * K + kt + scol];
        float4 a0 = *(const float4*)(s0);
        float4 a1 = *(const float4*)(s0 + 4);
        float4 b0 = *(const float4*)(s1);
        float4 b1 = *(const float4*)(s1 + 4);
        {
            bf16x8 v;
            v[0] = (__bf16)a0.x; v[1] = (__bf16)a0.y;
            v[2] = (__bf16)a0.z; v[3] = (__bf16)a0.w;
            v[4] = (__bf16)a1.x; v[5] = (__bf16)a1.y;
            v[6] = (__bf16)a1.z; v[7] = (__bf16)a1.w;
            *(bf16x8*)&Alds[srow * 64 + scol] = v;
            v[0] = (__bf16)b0.x; v[1] = (__bf16)b0.y;
            v[2] = (__bf16)b0.z; v[3] = (__bf16)b0.w;
            v[4] = (__bf16)b1.x; v[5] = (__bf16)b1.y;
            v[6] = (__bf16)b1.z; v[7] = (__bf16)b1.w;
            *(bf16x8*)&Alds[(srow + 64) * 64 + scol] = v;
        }
        asm volatile("s_waitcnt vmcnt(0)" ::: "memory");
        __syncthreads();

        // ---- compute: 2 k-halves x 4x4 MFMA per wave (64x64 out per wave)
#pragma unroll
        for (int ko = 0; ko < 64; ko += 32) {
            const int rbase = l & 15;
            const int kk = ko + (l >> 4) * 8;
            bf16x8 af[4], bfr[4];
#pragma unroll
            for (int i = 0; i < 4; ++i)
                af[i] = *(const bf16x8*)&Alds[(wr + i * 16 + rbase) * 64 + kk];
#pragma unroll
            for (int j = 0; j < 4; ++j)
                bfr[j] = *(const bf16x8*)&Blds[(wc + j * 16 + rbase) * 64 + kk];
#pragma unroll
            for (int i = 0; i < 4; ++i)
#pragma unroll
                for (int j = 0; j < 4; ++j)
                    acc[i][j] = __builtin_amdgcn_mfma_f32_16x16x32_bf16(
                        af[i], bfr[j], acc[i][j], 0, 0, 0);
        }
        __syncthreads();
    }

    // ---- epilogue: C/D layout col=lane&15, row=(lane>>4)*4+reg
#pragma unroll
    for (int j = 0; j < 4; ++j) {
        const int col = n0 + wc + j * 16 + (l & 15);
        const float bkv = bk[col];
#pragma unroll
        for (int i = 0; i < 4; ++i) {
            const int row0 = m0 + wr + i * 16 + (l >> 4) * 4;
#pragma unroll
            for (int r = 0; r < 4; ++r)
                kv[(size_t)(row0 + r) * NN + col] = (__bf16)(acc[i][j][r] + bkv);
        }
    }
}

// ---------------------------------------------------------------------------
// Kernel 2: per (b,h): logits -> masked softmax -> weighted sum.
// 512 blocks of 256 threads. XCD-swizzled so same-b blocks share an XCD L2.
// ---------------------------------------------------------------------------
__global__ __launch_bounds__(256) void attn_kernel(const __bf16* __restrict__ kv,
                                                   const float* __restrict__ q_emb,
                                                   const int* __restrict__ eos_idx,
                                                   float* __restrict__ out) {
    __shared__ float qlds[4 * 64];
    __shared__ float plds[4 * 1024];
    __shared__ float ssum[4];

    const int t = threadIdx.x;
    const int vid = ((blockIdx.x & 7) << 6) + (blockIdx.x >> 3);  // bijective, 512 blocks
    const int b = vid >> 4;
    const int h = vid & 15;
    const int eos = eos_idx[b];

    // q scaled by D^-0.5 = 1/8
    qlds[t] = q_emb[(size_t)h * 256 + t] * 0.125f;
    __syncthreads();

    const __bf16* kvb = kv + (size_t)b * 1024 * 1024 + h * 64;

    // ---- pass 1: logits[s][n]
#pragma unroll
    for (int i = 0; i < 4; ++i) {
        const int n = t + i * 256;
        float d0 = 0.f, d1 = 0.f, d2 = 0.f, d3 = 0.f;
        if (n <= eos) {
            const bf16x8* row = (const bf16x8*)(kvb + (size_t)n * 1024);
#pragma unroll
            for (int c = 0; c < 8; ++c) {
                bf16x8 v = row[c];
#pragma unroll
                for (int j = 0; j < 8; ++j) {
                    const float f = (float)v[j];
                    d0 += qlds[0 * 64 + c * 8 + j] * f;
                    d1 += qlds[1 * 64 + c * 8 + j] * f;
                    d2 += qlds[2 * 64 + c * 8 + j] * f;
                    d3 += qlds[3 * 64 + c * 8 + j] * f;
                }
            }
        } else {
            d0 = d1 = d2 = d3 = -INFINITY;
        }
        plds[0 * 1024 + n] = d0;
        plds[1 * 1024 + n] = d1;
        plds[2 * 1024 + n] = d2;
        plds[3 * 1024 + n] = d3;
    }
    __syncthreads();

    // ---- softmax: wave w handles subhead s=w
    const int w = t >> 6, l = t & 63;
    {
        float m = -INFINITY;
#pragma unroll
        for (int i = 0; i < 16; ++i) m = fmaxf(m, plds[w * 1024 + l + i * 64]);
#pragma unroll
        for (int off = 32; off; off >>= 1) m = fmaxf(m, __shfl_xor(m, off));
        float sum = 0.f;
#pragma unroll
        for (int i = 0; i < 16; ++i) {
            const int n = l + i * 64;
            const float p = __expf(plds[w * 1024 + n] - m);  // exp(-inf)=0
            plds[w * 1024 + n] = p;
            sum += p;
        }
#pragma unroll
        for (int off = 32; off; off >>= 1) sum += __shfl_xor(sum, off);
        if (l == 0) ssum[w] = sum;
    }
    __syncthreads();

    // ---- pass 2: out[s][d] = sum_n p[s][n]*kv[n][d] / ssum[s]
    const int s = t >> 6, d = t & 63;
    const __bf16* col = kvb + d;
    float acc = 0.f;
    int n = 0;
    for (; n + 4 <= eos + 1; n += 4) {
        const float f0 = (float)col[(size_t)(n + 0) * 1024];
        const float f1 = (float)col[(size_t)(n + 1) * 1024];
        const float f2 = (float)col[(size_t)(n + 2) * 1024];
        const float f3 = (float)col[(size_t)(n + 3) * 1024];
        acc += plds[s * 1024 + n + 0] * f0 + plds[s * 1024 + n + 1] * f1 +
               plds[s * 1024 + n + 2] * f2 + plds[s * 1024 + n + 3] * f3;
    }
    for (; n <= eos; ++n) acc += plds[s * 1024 + n] * (float)col[(size_t)n * 1024];

    out[((size_t)b * 64 + h * 4 + s) * 64 + d] = acc / ssum[s];
}

// ---------------------------------------------------------------------------
extern "C" void kernel_launch(void* const* d_in, const int* in_sizes, int n_in,
                              void* d_out, int out_size, void* d_ws, size_t ws_size,
                              hipStream_t stream) {
    const float* x     = (const float*)d_in[0];   // (32,1024,768)
    const int*   eos   = (const int*)d_in[1];     // (32,)
    const float* q_emb = (const float*)d_in[2];   // (16,4,64)
    const float* Wk    = (const float*)d_in[3];   // (768,1024)
    const float* bk    = (const float*)d_in[4];   // (1024,)
    float* out = (float*)d_out;

    __bf16* kv  = (__bf16*)d_ws;                              // 67,108,864 B
    __bf16* wkt = (__bf16*)((char*)d_ws + (size_t)67108864);  // 1,572,864 B

    transpose_wk<<<dim3(24, 32), 256, 0, stream>>>(Wk, wkt);
    gemm_kv<<<dim3(1024), 512, 0, stream>>>(x, wkt, bk, kv);
    attn_kernel<<<dim3(512), 256, 0, stream>>>(kv, q_emb, eos, out);
}

// Round 3
// 64.117 us; speedup vs baseline: 3.1163x; 2.4294x over previous
//
#include <hip/hip_runtime.h>
#include <hip/hip_bf16.h>
#include <stdint.h>

typedef float  f32x4  __attribute__((ext_vector_type(4)));
typedef __bf16 bf16x4 __attribute__((ext_vector_type(4)));
typedef __bf16 bf16x8 __attribute__((ext_vector_type(8)));
typedef unsigned int u32x2 __attribute__((ext_vector_type(2)));
typedef unsigned int u32x4 __attribute__((ext_vector_type(4)));

#define AS1 __attribute__((address_space(1)))
#define AS3 __attribute__((address_space(3)))

__device__ __forceinline__ void async_load16(const void* g, void* lds) {
    __builtin_amdgcn_global_load_lds((const AS1 unsigned int*)g,
                                     (AS3 unsigned int*)lds, 16, 0, 0);
}

// ---------------------------------------------------------------------------
// K1: qw[hs][k] = scale * sum_d q[h,s,d] * Wk[k, h*64+d]   (bf16 out, [hs][768])
// grid (12 kc, 16 h) x 256
// ---------------------------------------------------------------------------
__global__ __launch_bounds__(256) void qw_kernel(const float* __restrict__ q_emb,
                                                 const float* __restrict__ wk,
                                                 __bf16* __restrict__ qwT) {
    __shared__ float qlds[256];
    __shared__ float part[4096];  // [k 64][s 4][dseg 16]
    const int t = threadIdx.x;
    const int kc = blockIdx.x;   // 0..11
    const int h  = blockIdx.y;   // 0..15
    const int k0 = kc * 64;
    qlds[t] = q_emb[h * 256 + t] * 0.125f;   // scale = D^-0.5 = 1/8
    __syncthreads();
    const int dseg = t & 15;
    const int krow = t >> 4;   // 0..15
#pragma unroll
    for (int i = 0; i < 4; ++i) {
        const int k = i * 16 + krow;
        f32x4 wv = *(const f32x4*)&wk[(size_t)(k0 + k) * 1024 + h * 64 + dseg * 4];
#pragma unroll
        for (int s = 0; s < 4; ++s) {
            float p = qlds[s * 64 + dseg * 4 + 0] * wv[0]
                    + qlds[s * 64 + dseg * 4 + 1] * wv[1]
                    + qlds[s * 64 + dseg * 4 + 2] * wv[2]
                    + qlds[s * 64 + dseg * 4 + 3] * wv[3];
            part[k * 64 + s * 16 + dseg] = p;
        }
    }
    __syncthreads();
    const int k = t >> 2, s = t & 3;
    const float* pp = &part[k * 64 + s * 16];
    float sum = 0.f;
#pragma unroll
    for (int j = 0; j < 16; ++j) sum += pp[j];
    qwT[(h * 4 + s) * 768 + k0 + k] = (__bf16)sum;
}

// ---------------------------------------------------------------------------
// K2: logits[b][hs][n] = sum_k x[b,n,k]*qw[hs,k]
// M=32768 (BM=128 -> 256 blocks), N=64, K=768. 512 thr, 8 waves (4Mx2N).
// A (x f32->bf16) reg-staged dbuf; B (qw) via global_load_lds dbuf,
// both XOR-swizzled -> conflict-free frag reads. Epilogue transposes via LDS.
// ---------------------------------------------------------------------------
__global__ __launch_bounds__(512) void logits_kernel(const float* __restrict__ x,
                                                     const __bf16* __restrict__ qwT,
                                                     float* __restrict__ Lg) {
    __shared__ char smem[49152];
    char* Bl = smem;           // 2 x 8 KB  [col 64][k 64] bf16, XOR ((col&7)<<4)
    char* Al = smem + 16384;   // 2 x 16 KB [row 128][k 64] bf16, XOR ((row&7)<<4)
    const int t = threadIdx.x, l = t & 63, w = t >> 6;
    const int m0 = blockIdx.x * 128;
    const int bb = m0 >> 10, n0 = m0 & 1023;
    const int wrA = (w >> 1) * 32;  // 0..96  (m-dim)
    const int wcB = (w & 1) * 32;   // 0,32   (hs-dim)

    f32x4 acc[2][2];
#pragma unroll
    for (int i = 0; i < 2; ++i)
#pragma unroll
        for (int j = 0; j < 2; ++j) acc[i][j] = (f32x4)0.f;

    const int Bcol = t >> 3, Bseg = t & 7;
    const __bf16* qsrc = qwT + Bcol * 768 + (Bseg ^ (Bcol & 7)) * 8;
    const int Arow0 = t >> 4;   // + i*32
    const int Aseg = t & 15;

    f32x4 av[4];
    // ---- prologue (kt = 0)
    async_load16(qsrc, Bl + t * 16);
#pragma unroll
    for (int i = 0; i < 4; ++i)
        av[i] = *(const f32x4*)&x[(size_t)(m0 + i * 32 + Arow0) * 768 + Aseg * 4];
#pragma unroll
    for (int i = 0; i < 4; ++i) {
        const int row = i * 32 + Arow0;
        bf16x4 vv = {(__bf16)av[i][0], (__bf16)av[i][1], (__bf16)av[i][2], (__bf16)av[i][3]};
        *(bf16x4*)(Al + ((row * 128 + Aseg * 8) ^ ((row & 7) << 4))) = vv;
    }
    asm volatile("s_waitcnt vmcnt(0)" ::: "memory");
    __syncthreads();

    int buf = 0;
    for (int step = 0; step < 12; ++step) {
        const int nbuf = buf ^ 1;
        const bool more = (step + 1) < 12;
        if (more) {
            const int kt = (step + 1) * 64;
            async_load16(qsrc + kt, Bl + nbuf * 8192 + t * 16);
#pragma unroll
            for (int i = 0; i < 4; ++i)
                av[i] = *(const f32x4*)&x[(size_t)(m0 + i * 32 + Arow0) * 768 + kt + Aseg * 4];
        }
#pragma unroll
        for (int kh = 0; kh < 2; ++kh) {
            const int u = kh * 4 + (l >> 4);
            bf16x8 af[2], bfr[2];
#pragma unroll
            for (int i = 0; i < 2; ++i) {
                const int row = wrA + i * 16 + (l & 15);
                af[i] = *(const bf16x8*)(Al + buf * 16384 +
                                         ((row * 128 + u * 16) ^ ((row & 7) << 4)));
            }
#pragma unroll
            for (int j = 0; j < 2; ++j) {
                const int col = wcB + j * 16 + (l & 15);
                bfr[j] = *(const bf16x8*)(Bl + buf * 8192 +
                                          ((col * 128 + u * 16) ^ ((col & 7) << 4)));
            }
#pragma unroll
            for (int i = 0; i < 2; ++i)
#pragma unroll
                for (int j = 0; j < 2; ++j)
                    acc[i][j] = __builtin_amdgcn_mfma_f32_16x16x32_bf16(
                        af[i], bfr[j], acc[i][j], 0, 0, 0);
        }
        if (more) {
#pragma unroll
            for (int i = 0; i < 4; ++i) {
                const int row = i * 32 + Arow0;
                bf16x4 vv = {(__bf16)av[i][0], (__bf16)av[i][1], (__bf16)av[i][2], (__bf16)av[i][3]};
                *(bf16x4*)(Al + nbuf * 16384 + ((row * 128 + Aseg * 8) ^ ((row & 7) << 4))) = vv;
            }
        }
        asm volatile("s_waitcnt vmcnt(0)" ::: "memory");
        __syncthreads();
        buf = nbuf;
    }

    // ---- epilogue: frag -> LDS [hs 64][n 128] f32 -> coalesced global
#pragma unroll
    for (int i = 0; i < 2; ++i)
#pragma unroll
        for (int j = 0; j < 2; ++j) {
            const int hs = wcB + j * 16 + (l & 15);
            const int nb = wrA + i * 16 + (l >> 4) * 4;
            *(f32x4*)(smem + ((hs * 512 + nb * 4) ^ ((hs & 7) << 4))) = acc[i][j];
        }
    __syncthreads();
    const int hs = t >> 3;
#pragma unroll
    for (int i = 0; i < 4; ++i) {
        const int seg = (t & 7) + i * 8;
        f32x4 v = *(const f32x4*)(smem + ((hs * 512 + seg * 16) ^ ((hs & 7) << 4)));
        *(f32x4*)&Lg[(size_t)bb * 65536 + hs * 1024 + n0 + seg * 4] = v;
    }
}

// ---------------------------------------------------------------------------
// K3a: masked softmax over n per (b,hs).  P[b][hs][n] bf16 (normalized).
// 512 blocks (b,h) x 256 thr (wave = subhead s).
// ---------------------------------------------------------------------------
__global__ __launch_bounds__(256) void softmax_kernel(const float* __restrict__ Lg,
                                                      const int* __restrict__ eos_idx,
                                                      __bf16* __restrict__ P) {
    const int t = threadIdx.x, l = t & 63, s = t >> 6;
    const int b = blockIdx.x >> 4, h = blockIdx.x & 15;
    const int eos = eos_idx[b];
    const size_t base = (size_t)(b * 64 + h * 4 + s) * 1024;
    f32x4 v[4];
    float mx = -INFINITY;
#pragma unroll
    for (int i = 0; i < 4; ++i) {
        v[i] = *(const f32x4*)&Lg[base + i * 256 + l * 4];
#pragma unroll
        for (int j = 0; j < 4; ++j) {
            if (i * 256 + l * 4 + j > eos) v[i][j] = -INFINITY;
            mx = fmaxf(mx, v[i][j]);
        }
    }
#pragma unroll
    for (int off = 32; off; off >>= 1) mx = fmaxf(mx, __shfl_xor(mx, off));
    float sum = 0.f;
#pragma unroll
    for (int i = 0; i < 4; ++i)
#pragma unroll
        for (int j = 0; j < 4; ++j) {
            const float p = __expf(v[i][j] - mx);  // exp(-inf)=0 at masked
            v[i][j] = p;
            sum += p;
        }
#pragma unroll
    for (int off = 32; off; off >>= 1) sum += __shfl_xor(sum, off);
    const float inv = 1.0f / sum;
#pragma unroll
    for (int i = 0; i < 4; ++i) {
        bf16x4 pk = {(__bf16)(v[i][0] * inv), (__bf16)(v[i][1] * inv),
                     (__bf16)(v[i][2] * inv), (__bf16)(v[i][3] * inv)};
        *(bf16x4*)&P[base + i * 256 + l * 4] = pk;
    }
}

// ---------------------------------------------------------------------------
// K3b: y[b][hs][k] = sum_n P[b,hs,n] * x[b,n,k]
// per b: M=64(hs), N=768 (12 blocks of 64 k), K=1024(n). 384 blocks, 256 thr.
// A (P) via global_load_lds (src-permuted XOR swizzle); B (x^T) via per-lane-
// column dword loads (coalesced) + swizzled ds_write_b64 (conflict-free).
// ---------------------------------------------------------------------------
__global__ __launch_bounds__(256) void pv_kernel(const float* __restrict__ x,
                                                 const __bf16* __restrict__ P,
                                                 float* __restrict__ y) {
    __shared__ char smem[32768];
    char* Pl = smem;           // 2 x 8 KB  [hs 64][n 64] bf16, XOR ((row&7)<<4)
    char* Xl = smem + 16384;   // 2 x 8 KB  [k 64][n 64] bf16, XOR fK
    const int t = threadIdx.x, l = t & 63, w = t >> 6;
    const int vid = (blockIdx.x & 7) * 48 + (blockIdx.x >> 3);  // bijective XCD swizzle
    const int b = vid / 12, kc = vid % 12;
    const int k0 = kc * 64;
    const int wrA = (w >> 1) * 32, wcB = (w & 1) * 32;
    const __bf16* Pb = P + (size_t)b * 65536;
    const float* xb = x + (size_t)b * 786432 + k0 + l;   // this thread's k-column
    const int fK = ((l & 7) << 4) | (((l >> 3) & 1) << 3);

    f32x4 acc[2][2];
#pragma unroll
    for (int i = 0; i < 2; ++i)
#pragma unroll
        for (int j = 0; j < 2; ++j) acc[i][j] = (f32x4)0.f;

    const int Prow = t >> 3;   // + ii*32
    const int Pseg = t & 7;

    float xv[16];
    // ---- prologue (nt = 0)
#pragma unroll
    for (int ii = 0; ii < 2; ++ii) {
        const int row = ii * 32 + Prow;
        async_load16(Pb + row * 1024 + (Pseg ^ (row & 7)) * 8, Pl + ii * 4096 + t * 16);
    }
#pragma unroll
    for (int i = 0; i < 4; ++i)
#pragma unroll
        for (int j = 0; j < 4; ++j)
            xv[i * 4 + j] = xb[(size_t)(i * 16 + w * 4 + j) * 768];
#pragma unroll
    for (int i = 0; i < 4; ++i) {
        bf16x4 vv = {(__bf16)xv[i * 4 + 0], (__bf16)xv[i * 4 + 1],
                     (__bf16)xv[i * 4 + 2], (__bf16)xv[i * 4 + 3]};
        const int nb2 = (i * 16 + w * 4) * 2;
        *(bf16x4*)(Xl + ((l * 128 + nb2) ^ fK)) = vv;
    }
    asm volatile("s_waitcnt vmcnt(0)" ::: "memory");
    __syncthreads();

    int buf = 0;
    for (int step = 0; step < 16; ++step) {
        const int nbuf = buf ^ 1;
        const bool more = (step + 1) < 16;
        if (more) {
            const int nt = (step + 1) * 64;
#pragma unroll
            for (int ii = 0; ii < 2; ++ii) {
                const int row = ii * 32 + Prow;
                async_load16(Pb + row * 1024 + nt + (Pseg ^ (row & 7)) * 8,
                             Pl + nbuf * 8192 + ii * 4096 + t * 16);
            }
#pragma unroll
            for (int i = 0; i < 4; ++i)
#pragma unroll
                for (int j = 0; j < 4; ++j)
                    xv[i * 4 + j] = xb[(size_t)(nt + i * 16 + w * 4 + j) * 768];
        }
#pragma unroll
        for (int kh = 0; kh < 2; ++kh) {
            const int u = kh * 4 + (l >> 4);
            bf16x8 af[2], bfr[2];
#pragma unroll
            for (int i = 0; i < 2; ++i) {
                const int row = wrA + i * 16 + (l & 15);
                af[i] = *(const bf16x8*)(Pl + buf * 8192 +
                                         ((row * 128 + u * 16) ^ ((row & 7) << 4)));
            }
#pragma unroll
            for (int j = 0; j < 2; ++j) {
                const int kcol = wcB + j * 16 + (l & 15);
                const int fKc = ((kcol & 7) << 4) | (((kcol >> 3) & 1) << 3);
                const int addrA = kcol * 128 + kh * 64 + (l >> 4) * 16;
                u32x2 lo = *(const u32x2*)(Xl + buf * 8192 + (addrA ^ fKc));
                u32x2 hi = *(const u32x2*)(Xl + buf * 8192 + ((addrA + 8) ^ fKc));
                u32x4 uu = {lo[0], lo[1], hi[0], hi[1]};
                bfr[j] = __builtin_bit_cast(bf16x8, uu);
            }
#pragma unroll
            for (int i = 0; i < 2; ++i)
#pragma unroll
                for (int j = 0; j < 2; ++j)
                    acc[i][j] = __builtin_amdgcn_mfma_f32_16x16x32_bf16(
                        af[i], bfr[j], acc[i][j], 0, 0, 0);
        }
        if (more) {
#pragma unroll
            for (int i = 0; i < 4; ++i) {
                bf16x4 vv = {(__bf16)xv[i * 4 + 0], (__bf16)xv[i * 4 + 1],
                             (__bf16)xv[i * 4 + 2], (__bf16)xv[i * 4 + 3]};
                const int nb2 = (i * 16 + w * 4) * 2;
                *(bf16x4*)(Xl + nbuf * 8192 + ((l * 128 + nb2) ^ fK)) = vv;
            }
        }
        asm volatile("s_waitcnt vmcnt(0)" ::: "memory");
        __syncthreads();
        buf = nbuf;
    }

    // ---- epilogue: frag -> LDS [hs 64][k 64] f32 -> coalesced global
#pragma unroll
    for (int i = 0; i < 2; ++i)
#pragma unroll
        for (int j = 0; j < 2; ++j) {
            const int kcol = wcB + j * 16 + (l & 15);
#pragma unroll
            for (int r = 0; r < 4; ++r) {
                const int hs = wrA + i * 16 + (l >> 4) * 4 + r;
                *(float*)(smem + ((hs * 256 + kcol * 4) ^ ((hs & 7) << 4))) = acc[i][j][r];
            }
        }
    __syncthreads();
    const int hs2 = t >> 2;
#pragma unroll
    for (int i = 0; i < 4; ++i) {
        const int seg = (t & 3) + i * 4;
        f32x4 v = *(const f32x4*)(smem + ((hs2 * 256 + seg * 16) ^ ((hs2 & 7) << 4)));
        *(f32x4*)&y[(size_t)(b * 64 + hs2) * 768 + k0 + seg * 4] = v;
    }
}

// ---------------------------------------------------------------------------
// K4: out[b][hs][d] = sum_k y[b,hs,k]*Wk[k,h*64+d] + bk[h*64+d]
// 256 blocks = (h 16) x (b-pair 16), 256 thr = 4 k-partitions x 64 d.
// ---------------------------------------------------------------------------
__global__ __launch_bounds__(256) void out_kernel(const float* __restrict__ y,
                                                  const float* __restrict__ wk,
                                                  const float* __restrict__ bk,
                                                  float* __restrict__ out) {
    __shared__ float ylds[8 * 768];  // 24 KB
    __shared__ float red[2048];      // 8 KB
    const int t = threadIdx.x;
    const int vid = (blockIdx.x & 7) * 32 + (blockIdx.x >> 3);  // same-h grouped per XCD
    const int h = vid >> 4, bp = vid & 15;
#pragma unroll
    for (int r = 0; r < 8; ++r) {
        const int gb = bp * 2 + (r >> 2);
        const int hs = h * 4 + (r & 3);
#pragma unroll
        for (int i = 0; i < 3; ++i)
            ylds[r * 768 + i * 256 + t] = y[(size_t)(gb * 64 + hs) * 768 + i * 256 + t];
    }
    __syncthreads();
    const int kp = t >> 6, d = t & 63;
    float acc[8] = {0.f, 0.f, 0.f, 0.f, 0.f, 0.f, 0.f, 0.f};
    for (int i = 0; i < 48; ++i) {
        const int k = kp * 192 + i * 4;
        const float wv0 = wk[(size_t)(k + 0) * 1024 + h * 64 + d];
        const float wv1 = wk[(size_t)(k + 1) * 1024 + h * 64 + d];
        const float wv2 = wk[(size_t)(k + 2) * 1024 + h * 64 + d];
        const float wv3 = wk[(size_t)(k + 3) * 1024 + h * 64 + d];
#pragma unroll
        for (int r = 0; r < 8; ++r) {
            f32x4 yv = *(const f32x4*)&ylds[r * 768 + k];
            acc[r] += yv[0] * wv0 + yv[1] * wv1 + yv[2] * wv2 + yv[3] * wv3;
        }
    }
#pragma unroll
    for (int r = 0; r < 8; ++r) red[(r * 64 + d) * 4 + kp] = acc[r];
    __syncthreads();
#pragma unroll
    for (int i = 0; i < 2; ++i) {
        const int o = i * 256 + t;
        const int r = o >> 6, dd = o & 63;
        f32x4 pv = *(const f32x4*)&red[o * 4];
        const float s = pv[0] + pv[1] + pv[2] + pv[3] + bk[h * 64 + dd];
        const int gb = bp * 2 + (r >> 2);
        out[(size_t)(gb * 64 + h * 4 + (r & 3)) * 64 + dd] = s;
    }
}

// ---------------------------------------------------------------------------
extern "C" void kernel_launch(void* const* d_in, const int* in_sizes, int n_in,
                              void* d_out, int out_size, void* d_ws, size_t ws_size,
                              hipStream_t stream) {
    const float* x     = (const float*)d_in[0];   // (32,1024,768)
    const int*   eos   = (const int*)d_in[1];     // (32,)
    const float* q_emb = (const float*)d_in[2];   // (16,4,64)
    const float* Wk    = (const float*)d_in[3];   // (768,1024)
    const float* bk    = (const float*)d_in[4];   // (1024,)
    float* out = (float*)d_out;

    char* ws = (char*)d_ws;
    __bf16* qwT = (__bf16*)ws;                                   // 96 KB  [hs 64][k 768]
    float*  Lg  = (float*)(ws + 131072);                         // 8 MB   [b][hs][n]
    __bf16* P   = (__bf16*)(ws + 131072 + 8388608);              // 4 MB   [b][hs][n]
    float*  y   = (float*)(ws + 131072 + 8388608 + 4194304);     // 6 MB   [b][hs][k]

    qw_kernel<<<dim3(12, 16), 256, 0, stream>>>(q_emb, Wk, qwT);
    logits_kernel<<<dim3(256), 512, 0, stream>>>(x, qwT, Lg);
    softmax_kernel<<<dim3(512), 256, 0, stream>>>(Lg, eos, P);
    pv_kernel<<<dim3(384), 256, 0, stream>>>(x, P, y);
    out_kernel<<<dim3(256), 256, 0, stream>>>(y, Wk, bk, out);
}

// Round 4
// 63.833 us; speedup vs baseline: 3.1301x; 1.0044x over previous
//
#include <hip/hip_runtime.h>
#include <hip/hip_bf16.h>
#include <stdint.h>

typedef float  f32x4  __attribute__((ext_vector_type(4)));
typedef __bf16 bf16x4 __attribute__((ext_vector_type(4)));
typedef __bf16 bf16x8 __attribute__((ext_vector_type(8)));
typedef unsigned int u32x2 __attribute__((ext_vector_type(2)));
typedef unsigned int u32x4 __attribute__((ext_vector_type(4)));

#define AS1 __attribute__((address_space(1)))
#define AS3 __attribute__((address_space(3)))

__device__ __forceinline__ void async_load16(const void* g, void* lds) {
    __builtin_amdgcn_global_load_lds((const AS1 unsigned int*)g,
                                     (AS3 unsigned int*)lds, 16, 0, 0);
}

// ---------------------------------------------------------------------------
// K1: qw[hs][k] = scale * sum_d q[h,s,d] * Wk[k, h*64+d]   (bf16 out, [hs][768])
// grid (12 kc, 16 h) x 256
// ---------------------------------------------------------------------------
__global__ __launch_bounds__(256) void qw_kernel(const float* __restrict__ q_emb,
                                                 const float* __restrict__ wk,
                                                 __bf16* __restrict__ qwT) {
    __shared__ float qlds[256];
    __shared__ float part[4096];  // [k 64][s 4][dseg 16]
    const int t = threadIdx.x;
    const int kc = blockIdx.x;   // 0..11
    const int h  = blockIdx.y;   // 0..15
    const int k0 = kc * 64;
    qlds[t] = q_emb[h * 256 + t] * 0.125f;   // scale = D^-0.5 = 1/8
    __syncthreads();
    const int dseg = t & 15;
    const int krow = t >> 4;   // 0..15
#pragma unroll
    for (int i = 0; i < 4; ++i) {
        const int k = i * 16 + krow;
        f32x4 wv = *(const f32x4*)&wk[(size_t)(k0 + k) * 1024 + h * 64 + dseg * 4];
#pragma unroll
        for (int s = 0; s < 4; ++s) {
            float p = qlds[s * 64 + dseg * 4 + 0] * wv[0]
                    + qlds[s * 64 + dseg * 4 + 1] * wv[1]
                    + qlds[s * 64 + dseg * 4 + 2] * wv[2]
                    + qlds[s * 64 + dseg * 4 + 3] * wv[3];
            part[k * 64 + s * 16 + dseg] = p;
        }
    }
    __syncthreads();
    const int k = t >> 2, s = t & 3;
    const float* pp = &part[k * 64 + s * 16];
    float sum = 0.f;
#pragma unroll
    for (int j = 0; j < 16; ++j) sum += pp[j];
    qwT[(h * 4 + s) * 768 + k0 + k] = (__bf16)sum;
}

// ---------------------------------------------------------------------------
// K2: logits[b][hs][n] = sum_k x[b,n,k]*qw[hs,k], eos-masked (-inf), plus
// per-(b,chunk,hs) softmax partials (max m_c, sum s_c = sum exp(l-m_c)).
// M=32768 (BM=128 -> 256 blocks), N=64, K=768. 512 thr, 8 waves (4Mx2N).
// ---------------------------------------------------------------------------
__global__ __launch_bounds__(512) void logits_kernel(const float* __restrict__ x,
                                                     const __bf16* __restrict__ qwT,
                                                     const int* __restrict__ eos_idx,
                                                     float* __restrict__ Lg,
                                                     float* __restrict__ partials) {
    __shared__ char smem[49152];
    char* Bl = smem;           // 2 x 8 KB  [col 64][k 64] bf16, XOR ((col&7)<<4)
    char* Al = smem + 16384;   // 2 x 16 KB [row 128][k 64] bf16, XOR ((row&7)<<4)
    const int t = threadIdx.x, l = t & 63, w = t >> 6;
    const int m0 = blockIdx.x * 128;
    const int bb = m0 >> 10, n0 = m0 & 1023;
    const int chunk = blockIdx.x & 7;
    const int wrA = (w >> 1) * 32;  // 0..96  (m-dim)
    const int wcB = (w & 1) * 32;   // 0,32   (hs-dim)

    f32x4 acc[2][2];
#pragma unroll
    for (int i = 0; i < 2; ++i)
#pragma unroll
        for (int j = 0; j < 2; ++j) acc[i][j] = (f32x4)0.f;

    const int Bcol = t >> 3, Bseg = t & 7;
    const __bf16* qsrc = qwT + Bcol * 768 + (Bseg ^ (Bcol & 7)) * 8;
    const int Arow0 = t >> 4;   // + i*32
    const int Aseg = t & 15;

    f32x4 av[4];
    // ---- prologue (kt = 0)
    async_load16(qsrc, Bl + t * 16);
#pragma unroll
    for (int i = 0; i < 4; ++i)
        av[i] = *(const f32x4*)&x[(size_t)(m0 + i * 32 + Arow0) * 768 + Aseg * 4];
#pragma unroll
    for (int i = 0; i < 4; ++i) {
        const int row = i * 32 + Arow0;
        bf16x4 vv = {(__bf16)av[i][0], (__bf16)av[i][1], (__bf16)av[i][2], (__bf16)av[i][3]};
        *(bf16x4*)(Al + ((row * 128 + Aseg * 8) ^ ((row & 7) << 4))) = vv;
    }
    asm volatile("s_waitcnt vmcnt(0)" ::: "memory");
    __syncthreads();

    int buf = 0;
    for (int step = 0; step < 12; ++step) {
        const int nbuf = buf ^ 1;
        const bool more = (step + 1) < 12;
        if (more) {
            const int kt = (step + 1) * 64;
            async_load16(qsrc + kt, Bl + nbuf * 8192 + t * 16);
#pragma unroll
            for (int i = 0; i < 4; ++i)
                av[i] = *(const f32x4*)&x[(size_t)(m0 + i * 32 + Arow0) * 768 + kt + Aseg * 4];
        }
#pragma unroll
        for (int kh = 0; kh < 2; ++kh) {
            const int u = kh * 4 + (l >> 4);
            bf16x8 af[2], bfr[2];
#pragma unroll
            for (int i = 0; i < 2; ++i) {
                const int row = wrA + i * 16 + (l & 15);
                af[i] = *(const bf16x8*)(Al + buf * 16384 +
                                         ((row * 128 + u * 16) ^ ((row & 7) << 4)));
            }
#pragma unroll
            for (int j = 0; j < 2; ++j) {
                const int col = wcB + j * 16 + (l & 15);
                bfr[j] = *(const bf16x8*)(Bl + buf * 8192 +
                                          ((col * 128 + u * 16) ^ ((col & 7) << 4)));
            }
#pragma unroll
            for (int i = 0; i < 2; ++i)
#pragma unroll
                for (int j = 0; j < 2; ++j)
                    acc[i][j] = __builtin_amdgcn_mfma_f32_16x16x32_bf16(
                        af[i], bfr[j], acc[i][j], 0, 0, 0);
        }
        if (more) {
#pragma unroll
            for (int i = 0; i < 4; ++i) {
                const int row = i * 32 + Arow0;
                bf16x4 vv = {(__bf16)av[i][0], (__bf16)av[i][1], (__bf16)av[i][2], (__bf16)av[i][3]};
                *(bf16x4*)(Al + nbuf * 16384 + ((row * 128 + Aseg * 8) ^ ((row & 7) << 4))) = vv;
            }
        }
        asm volatile("s_waitcnt vmcnt(0)" ::: "memory");
        __syncthreads();
        buf = nbuf;
    }

    // ---- epilogue: frag -> LDS [hs 64][n 128] f32 -> mask, stats, store
#pragma unroll
    for (int i = 0; i < 2; ++i)
#pragma unroll
        for (int j = 0; j < 2; ++j) {
            const int hs = wcB + j * 16 + (l & 15);
            const int nb = wrA + i * 16 + (l >> 4) * 4;
            *(f32x4*)(smem + ((hs * 512 + nb * 4) ^ ((hs & 7) << 4))) = acc[i][j];
        }
    __syncthreads();
    const int eosb = eos_idx[bb];
    const int hs = t >> 3;
    f32x4 vv[4];
    float mx = -INFINITY;
#pragma unroll
    for (int i = 0; i < 4; ++i) {
        const int seg = (t & 7) + i * 8;
        f32x4 v = *(const f32x4*)(smem + ((hs * 512 + seg * 16) ^ ((hs & 7) << 4)));
#pragma unroll
        for (int j = 0; j < 4; ++j) {
            if (n0 + seg * 4 + j > eosb) v[j] = -INFINITY;
            mx = fmaxf(mx, v[j]);
        }
        vv[i] = v;
        *(f32x4*)&Lg[(size_t)bb * 65536 + hs * 1024 + n0 + seg * 4] = v;
    }
    // reduce over the 8 lanes (t&7) sharing this hs
#pragma unroll
    for (int off = 1; off < 8; off <<= 1) mx = fmaxf(mx, __shfl_xor(mx, off));
    float sl = 0.f;
    if (mx > -INFINITY) {
#pragma unroll
        for (int i = 0; i < 4; ++i)
#pragma unroll
            for (int j = 0; j < 4; ++j) sl += __expf(vv[i][j] - mx);  // exp(-inf)=0
    }
#pragma unroll
    for (int off = 1; off < 8; off <<= 1) sl += __shfl_xor(sl, off);
    if ((t & 7) == 0) {
        float2 st = {mx, sl};
        *(float2*)&partials[(size_t)(((bb * 8 + chunk) * 64) + hs) * 2] = st;
    }
}

// ---------------------------------------------------------------------------
// K3: y[b][hs][k] = sum_n softmax(Lg)[b,hs,n] * x[b,n,k]   (softmax fused)
// per b: M=64(hs), N=768 (12 blocks of 64 k), K=1024(n). 384 blocks, 256 thr.
// A (P = exp(Lg-m)*inv) compute-staged into swizzled LDS; B (x^T) via per-
// lane-column dword loads (coalesced) + swizzled ds_write (conflict-free).
// ---------------------------------------------------------------------------
__global__ __launch_bounds__(256) void pv_kernel(const float* __restrict__ x,
                                                 const float* __restrict__ Lg,
                                                 const float* __restrict__ partials,
                                                 float* __restrict__ y) {
    __shared__ char smem[32768];
    char* Pl = smem;           // 2 x 8 KB  [hs 64][n 64] bf16, XOR ((row&7)<<4)
    char* Xl = smem + 16384;   // 2 x 8 KB  [k 64][n 64] bf16, XOR fK
    const int t = threadIdx.x, l = t & 63, w = t >> 6;
    const int vid = (blockIdx.x & 7) * 48 + (blockIdx.x >> 3);  // bijective XCD swizzle
    const int b = vid / 12, kc = vid % 12;
    const int k0 = kc * 64;
    const int wrA = (w >> 1) * 32, wcB = (w & 1) * 32;
    const float* Lgb = Lg + (size_t)b * 65536;
    const float* xb = x + (size_t)b * 786432 + k0 + l;   // this thread's k-column
    const int fK = ((l & 7) << 4) | (((l >> 3) & 1) << 3);

    // ---- combine softmax partials for this thread's two staging rows
    const int r0 = t >> 3, r1 = 32 + (t >> 3);
    float m0r, i0r, m1r, i1r;
    {
        const float* pb = partials + (size_t)b * 1024;  // [chunk 8][hs 64] float2
        float m = -INFINITY, m2 = -INFINITY;
#pragma unroll
        for (int c = 0; c < 8; ++c) {
            m  = fmaxf(m,  pb[(c * 64 + r0) * 2]);
            m2 = fmaxf(m2, pb[(c * 64 + r1) * 2]);
        }
        float s = 0.f, s2 = 0.f;
#pragma unroll
        for (int c = 0; c < 8; ++c) {
            float2 p0 = *(const float2*)&pb[(c * 64 + r0) * 2];
            float2 p1 = *(const float2*)&pb[(c * 64 + r1) * 2];
            s  += p0.y * __expf(p0.x - m);
            s2 += p1.y * __expf(p1.x - m2);
        }
        m0r = m; i0r = 1.0f / s;
        m1r = m2; i1r = 1.0f / s2;
    }
    // element n-offsets within a 64-tile for compute-staging (source swizzle)
    const int n0s0 = (((t & 7) ^ (r0 & 7)) * 8);
    const int n0s1 = (((t & 7) ^ (r1 & 7)) * 8);

    f32x4 acc[2][2];
#pragma unroll
    for (int i = 0; i < 2; ++i)
#pragma unroll
        for (int j = 0; j < 2; ++j) acc[i][j] = (f32x4)0.f;

    float xv[16];
    // ---- prologue (nt = 0): stage P and X for tile 0
#pragma unroll
    for (int ii = 0; ii < 2; ++ii) {
        const int r = ii ? r1 : r0;
        const int ns = ii ? n0s1 : n0s0;
        const float mr = ii ? m1r : m0r, ir = ii ? i1r : i0r;
        f32x4 lo = *(const f32x4*)&Lgb[(size_t)r * 1024 + ns];
        f32x4 hi = *(const f32x4*)&Lgb[(size_t)r * 1024 + ns + 4];
        bf16x8 pk;
#pragma unroll
        for (int j = 0; j < 4; ++j) pk[j]     = (__bf16)(__expf(lo[j] - mr) * ir);
#pragma unroll
        for (int j = 0; j < 4; ++j) pk[4 + j] = (__bf16)(__expf(hi[j] - mr) * ir);
        *(bf16x8*)(Pl + ii * 4096 + t * 16) = pk;
    }
#pragma unroll
    for (int i = 0; i < 4; ++i)
#pragma unroll
        for (int j = 0; j < 4; ++j)
            xv[i * 4 + j] = xb[(size_t)(i * 16 + w * 4 + j) * 768];
#pragma unroll
    for (int i = 0; i < 4; ++i) {
        bf16x4 vv = {(__bf16)xv[i * 4 + 0], (__bf16)xv[i * 4 + 1],
                     (__bf16)xv[i * 4 + 2], (__bf16)xv[i * 4 + 3]};
        const int nb2 = (i * 16 + w * 4) * 2;
        *(bf16x4*)(Xl + ((l * 128 + nb2) ^ fK)) = vv;
    }
    __syncthreads();

    int buf = 0;
    for (int step = 0; step < 16; ++step) {
        const int nbuf = buf ^ 1;
        const bool more = (step + 1) < 16;
        if (more) {
            const int nt = (step + 1) * 64;
#pragma unroll
            for (int ii = 0; ii < 2; ++ii) {
                const int r = ii ? r1 : r0;
                const int ns = ii ? n0s1 : n0s0;
                const float mr = ii ? m1r : m0r, ir = ii ? i1r : i0r;
                f32x4 lo = *(const f32x4*)&Lgb[(size_t)r * 1024 + nt + ns];
                f32x4 hi = *(const f32x4*)&Lgb[(size_t)r * 1024 + nt + ns + 4];
                bf16x8 pk;
#pragma unroll
                for (int j = 0; j < 4; ++j) pk[j]     = (__bf16)(__expf(lo[j] - mr) * ir);
#pragma unroll
                for (int j = 0; j < 4; ++j) pk[4 + j] = (__bf16)(__expf(hi[j] - mr) * ir);
                *(bf16x8*)(Pl + nbuf * 8192 + ii * 4096 + t * 16) = pk;
            }
#pragma unroll
            for (int i = 0; i < 4; ++i)
#pragma unroll
                for (int j = 0; j < 4; ++j)
                    xv[i * 4 + j] = xb[(size_t)(nt + i * 16 + w * 4 + j) * 768];
        }
#pragma unroll
        for (int kh = 0; kh < 2; ++kh) {
            const int u = kh * 4 + (l >> 4);
            bf16x8 af[2], bfr[2];
#pragma unroll
            for (int i = 0; i < 2; ++i) {
                const int row = wrA + i * 16 + (l & 15);
                af[i] = *(const bf16x8*)(Pl + buf * 8192 +
                                         ((row * 128 + u * 16) ^ ((row & 7) << 4)));
            }
#pragma unroll
            for (int j = 0; j < 2; ++j) {
                const int kcol = wcB + j * 16 + (l & 15);
                const int fKc = ((kcol & 7) << 4) | (((kcol >> 3) & 1) << 3);
                const int addrA = kcol * 128 + kh * 64 + (l >> 4) * 16;
                u32x2 lo = *(const u32x2*)(Xl + buf * 8192 + (addrA ^ fKc));
                u32x2 hi = *(const u32x2*)(Xl + buf * 8192 + ((addrA + 8) ^ fKc));
                u32x4 uu = {lo[0], lo[1], hi[0], hi[1]};
                bfr[j] = __builtin_bit_cast(bf16x8, uu);
            }
#pragma unroll
            for (int i = 0; i < 2; ++i)
#pragma unroll
                for (int j = 0; j < 2; ++j)
                    acc[i][j] = __builtin_amdgcn_mfma_f32_16x16x32_bf16(
                        af[i], bfr[j], acc[i][j], 0, 0, 0);
        }
        if (more) {
#pragma unroll
            for (int i = 0; i < 4; ++i) {
                bf16x4 vv = {(__bf16)xv[i * 4 + 0], (__bf16)xv[i * 4 + 1],
                             (__bf16)xv[i * 4 + 2], (__bf16)xv[i * 4 + 3]};
                const int nb2 = (i * 16 + w * 4) * 2;
                *(bf16x4*)(Xl + nbuf * 8192 + ((l * 128 + nb2) ^ fK)) = vv;
            }
        }
        __syncthreads();
        buf = nbuf;
    }

    // ---- epilogue: frag -> LDS [hs 64][k 64] f32 -> coalesced global
#pragma unroll
    for (int i = 0; i < 2; ++i)
#pragma unroll
        for (int j = 0; j < 2; ++j) {
            const int kcol = wcB + j * 16 + (l & 15);
#pragma unroll
            for (int r = 0; r < 4; ++r) {
                const int hs2 = wrA + i * 16 + (l >> 4) * 4 + r;
                *(float*)(smem + ((hs2 * 256 + kcol * 4) ^ ((hs2 & 7) << 4))) = acc[i][j][r];
            }
        }
    __syncthreads();
    const int hs2 = t >> 2;
#pragma unroll
    for (int i = 0; i < 4; ++i) {
        const int seg = (t & 3) + i * 4;
        f32x4 v = *(const f32x4*)(smem + ((hs2 * 256 + seg * 16) ^ ((hs2 & 7) << 4)));
        *(f32x4*)&y[(size_t)(b * 64 + hs2) * 768 + k0 + seg * 4] = v;
    }
}

// ---------------------------------------------------------------------------
// K4: out[b][hs][d] = sum_k y[b,hs,k]*Wk[k,h*64+d] + bk[h*64+d]
// 256 blocks = (h 16) x (b-pair 16), 256 thr = 4 k-partitions x 64 d.
// ---------------------------------------------------------------------------
__global__ __launch_bounds__(256) void out_kernel(const float* __restrict__ y,
                                                  const float* __restrict__ wk,
                                                  const float* __restrict__ bk,
                                                  float* __restrict__ out) {
    __shared__ float ylds[8 * 768];  // 24 KB
    __shared__ float red[2048];      // 8 KB
    const int t = threadIdx.x;
    const int vid = (blockIdx.x & 7) * 32 + (blockIdx.x >> 3);  // same-h grouped per XCD
    const int h = vid >> 4, bp = vid & 15;
#pragma unroll
    for (int r = 0; r < 8; ++r) {
        const int gb = bp * 2 + (r >> 2);
        const int hs = h * 4 + (r & 3);
#pragma unroll
        for (int i = 0; i < 3; ++i)
            ylds[r * 768 + i * 256 + t] = y[(size_t)(gb * 64 + hs) * 768 + i * 256 + t];
    }
    __syncthreads();
    const int kp = t >> 6, d = t & 63;
    float acc[8] = {0.f, 0.f, 0.f, 0.f, 0.f, 0.f, 0.f, 0.f};
    for (int i = 0; i < 48; ++i) {
        const int k = kp * 192 + i * 4;
        const float wv0 = wk[(size_t)(k + 0) * 1024 + h * 64 + d];
        const float wv1 = wk[(size_t)(k + 1) * 1024 + h * 64 + d];
        const float wv2 = wk[(size_t)(k + 2) * 1024 + h * 64 + d];
        const float wv3 = wk[(size_t)(k + 3) * 1024 + h * 64 + d];
#pragma unroll
        for (int r = 0; r < 8; ++r) {
            f32x4 yv = *(const f32x4*)&ylds[r * 768 + k];
            acc[r] += yv[0] * wv0 + yv[1] * wv1 + yv[2] * wv2 + yv[3] * wv3;
        }
    }
#pragma unroll
    for (int r = 0; r < 8; ++r) red[(r * 64 + d) * 4 + kp] = acc[r];
    __syncthreads();
#pragma unroll
    for (int i = 0; i < 2; ++i) {
        const int o = i * 256 + t;
        const int r = o >> 6, dd = o & 63;
        f32x4 pv = *(const f32x4*)&red[o * 4];
        const float s = pv[0] + pv[1] + pv[2] + pv[3] + bk[h * 64 + dd];
        const int gb = bp * 2 + (r >> 2);
        out[(size_t)(gb * 64 + h * 4 + (r & 3)) * 64 + dd] = s;
    }
}

// ---------------------------------------------------------------------------
extern "C" void kernel_launch(void* const* d_in, const int* in_sizes, int n_in,
                              void* d_out, int out_size, void* d_ws, size_t ws_size,
                              hipStream_t stream) {
    const float* x     = (const float*)d_in[0];   // (32,1024,768)
    const int*   eos   = (const int*)d_in[1];     // (32,)
    const float* q_emb = (const float*)d_in[2];   // (16,4,64)
    const float* Wk    = (const float*)d_in[3];   // (768,1024)
    const float* bk    = (const float*)d_in[4];   // (1024,)
    float* out = (float*)d_out;

    char* ws = (char*)d_ws;
    __bf16* qwT      = (__bf16*)ws;                          // 96 KB  [hs 64][k 768]
    float*  Lg       = (float*)(ws + 131072);                // 8 MB   [b][hs][n]
    float*  partials = (float*)(ws + 131072 + 8388608);      // 128 KB [b][chunk][hs][2]
    float*  y        = (float*)(ws + 131072 + 8388608 + 131072);  // 6 MB [b][hs][k]

    qw_kernel<<<dim3(12, 16), 256, 0, stream>>>(q_emb, Wk, qwT);
    logits_kernel<<<dim3(256), 512, 0, stream>>>(x, qwT, eos, Lg, partials);
    pv_kernel<<<dim3(384), 256, 0, stream>>>(x, Lg, partials, y);
    out_kernel<<<dim3(256), 256, 0, stream>>>(y, Wk, bk, out);
}